// Round 3
// baseline (519.927 us; speedup 1.0000x reference)
//
#include <hip/hip_runtime.h>

#define BSZ 32
#define DIM 64
#define SEQ 2048
#define KE  1024
#define ETS 68   // padded ws row stride in floats: 64 e-values + b2 + 3 pad (16B-aligned)

// output offsets in floats
#define O0 0ull            // quantized_st [BS][D][S]
#define O1 4194304ull      // loss (scalar)
#define O2 4194305ull      // one_hot [BS][K][S]
#define O3 71303169ull     // indices [BS][S] (as float)
#define O4 71368705ull     // distance [BS][K][S]
#define O5 138477569ull    // unquantized [BS*S][D]
#define O6 142671873ull    // embeddings.T [K][D]

// Kernel 0: transpose E -> out6 + padded ws copy (row: 64 e + b2); zero loss.
__global__ __launch_bounds__(256) void vq_prep(const float* __restrict__ E,
                                               float* __restrict__ out,
                                               float* __restrict__ et_ws) {
    __shared__ float T[64][65];
    const int tid  = threadIdx.x;
    const int lane = tid & 63;
    const int sub  = tid >> 6;
    const int k0   = blockIdx.x * 64;
    for (int dd = 0; dd < 16; ++dd) {
        int d = dd * 4 + sub;
        T[d][lane] = E[(size_t)d * KE + k0 + lane];
    }
    __syncthreads();
    for (int ii = 0; ii < 16; ++ii) {
        int kl = ii * 4 + sub;
        float v = T[lane][kl];                        // stride-65: conflict-free
        out[O6 + (size_t)(k0 + kl) * 64 + lane] = v;
        et_ws[(size_t)(k0 + kl) * ETS + lane]    = v;
    }
    if (tid < 64) {
        float s = 0.f;
        #pragma unroll
        for (int d = 0; d < 64; ++d) {
            float v = T[d][tid];
            s = fmaf(v, v, s);
        }
        et_ws[(size_t)(k0 + tid) * ETS + 64] = s;     // b2 rides with the row
    }
    if (blockIdx.x == 0 && tid == 0) out[O1] = 0.f;
}

// Kernel 1: distances via broadcast vector loads of e-rows (L2-resident),
// fused one_hot zeros, argmin, indices/one_hot-fix/quantized/loss.
// grid = 32 batches * 32 s-tiles; block = 256 (4 waves); lane = s; wave = k-range.
__global__ __launch_bounds__(256, 4) void vq_main(const float* __restrict__ x,
                                                  const float* __restrict__ et,
                                                  float* __restrict__ out) {
    __shared__ float mD[4][64];
    __shared__ int   mK[4][64];
    __shared__ int   idxs[64];

    const int tid  = threadIdx.x;
    const int lane = tid & 63;
    const int wv   = tid >> 6;     // NOT readfirstlane: keep addresses in VGPRs
    const int b    = blockIdx.x >> 5;
    const int s0   = (blockIdx.x & 31) << 6;
    const int s    = s0 + lane;

    // x row for this lane's s: 64 regs, static indexing only
    const float* xp = x + ((size_t)b << 17) + s;   // D*S = 2^17
    float xr[64];
    #pragma unroll
    for (int d = 0; d < 64; ++d) xr[d] = xp[(size_t)d << 11];   // S = 2^11
    float a2 = 0.f;
    #pragma unroll
    for (int d = 0; d < 64; ++d) a2 = fmaf(xr[d], xr[d], a2);

    float bestD = 3.4e38f;
    const int kbase = wv << 8;     // wave owns k in [wv*256, +256), ascending
    int   bestK = kbase;
    float* outD = out + O4 + ((size_t)b << 21) + s;   // K*S = 2^21
    float* outH = out + O2 + ((size_t)b << 21) + s;

    #pragma unroll 2
    for (int kk = 0; kk < 256; ++kk) {
        const int k = kbase + kk;
        const float4* ep = (const float4*)(et + (size_t)k * ETS);  // wave-uniform addr -> 1-txn broadcast
        float4 eb = ep[16];            // .x = b2[k], same load stream
        float d0 = 0.f, d1 = 0.f, d2 = 0.f, d3 = 0.f;
        #pragma unroll
        for (int g = 0; g < 16; ++g) {
            float4 e = ep[g];
            d0 = fmaf(xr[4*g+0], e.x, d0);
            d1 = fmaf(xr[4*g+1], e.y, d1);
            d2 = fmaf(xr[4*g+2], e.z, d2);
            d3 = fmaf(xr[4*g+3], e.w, d3);
        }
        float dist = fmaf(-2.f, (d0 + d1) + (d2 + d3), a2 + eb.x);
        outD[(size_t)k << 11] = dist;   // coalesced over s
        outH[(size_t)k << 11] = 0.f;    // fused one_hot zero, same shape
        if (dist < bestD) { bestD = dist; bestK = k; }  // first-occurrence within wave
    }

    mD[wv][lane] = bestD;
    mK[wv][lane] = bestK;
    __syncthreads();   // also drains vmcnt: all one_hot zeros complete before the 1.0 fix
    if (tid < 64) {
        float bD = mD[0][tid]; int bK = mK[0][tid];
        #pragma unroll
        for (int w = 1; w < 4; ++w) {
            float dw = mD[w][tid]; int kw = mK[w][tid];
            if (dw < bD || (dw == bD && kw < bK)) { bD = dw; bK = kw; }  // global first-min
        }
        idxs[tid] = bK;
        out[O3 + (size_t)b * SEQ + s0 + tid] = (float)bK;
        out[O2 + ((size_t)b << 21) + ((size_t)bK << 11) + s0 + tid] = 1.f;  // one_hot fix
    }
    __syncthreads();
    const int myidx = idxs[lane];

    // quantized_st + loss: wave 0 only (has x in regs, lane = s)
    if (wv == 0) {
        const float* q = et + (size_t)myidx * ETS;
        float* outQ = out + O0 + ((size_t)b << 17) + s;
        float lsum = 0.f;
        #pragma unroll
        for (int d = 0; d < 64; ++d) {
            float qv = q[d];
            outQ[(size_t)d << 11] = qv;     // coalesced over s
            float df = qv - xr[d];
            lsum = fmaf(df, df, lsum);
        }
        #pragma unroll
        for (int m = 32; m >= 1; m >>= 1) lsum += __shfl_xor(lsum, m, 64);
        if (lane == 0) atomicAdd(out + O1, lsum * (2.f / 4194304.f));
    }
}

// Kernel 2: unquantized = x transposed to [BS*S][D]
__global__ __launch_bounds__(256) void vq_unq(const float* __restrict__ x,
                                              float* __restrict__ out) {
    __shared__ float T[64][65];
    const int tid  = threadIdx.x;
    const int lane = tid & 63;
    const int sub  = tid >> 6;
    const int b    = blockIdx.x >> 5;
    const int s0   = (blockIdx.x & 31) << 6;
    const float* xp = x + ((size_t)b << 17) + s0;
    for (int dd = 0; dd < 16; ++dd) {
        int d = dd * 4 + sub;
        T[d][lane] = xp[((size_t)d << 11) + lane];
    }
    __syncthreads();
    float* op = out + O5 + (((size_t)b << 11) + s0) * 64;
    for (int ii = 0; ii < 16; ++ii) {
        int sl = ii * 4 + sub;
        op[(size_t)sl * 64 + lane] = T[lane][sl];
    }
}

extern "C" void kernel_launch(void* const* d_in, const int* in_sizes, int n_in,
                              void* d_out, int out_size, void* d_ws, size_t ws_size,
                              hipStream_t stream) {
    const float* x = (const float*)d_in[0];
    const float* E = (const float*)d_in[1];
    float* out   = (float*)d_out;
    float* et_ws = (float*)d_ws;          // 1024 rows * 68 floats (16B-aligned rows)
    vq_prep<<<16, 256, 0, stream>>>(E, out, et_ws);
    vq_main<<<1024, 256, 0, stream>>>(x, et_ws, out);
    vq_unq<<<1024, 256, 0, stream>>>(x, out);
}

// Round 4
// 293.742 us; speedup vs baseline: 1.7700x; 1.7700x over previous
//
#include <hip/hip_runtime.h>

#define BSZ 32
#define DIM 64
#define SEQ 2048
#define KE  1024
#define KC  128   // k-chunk staged in LDS
#define ST  128   // s-tile per block

// output offsets in floats
#define O0 0ull            // quantized_st [BS][D][S]
#define O1 4194304ull      // loss (scalar)
#define O2 4194305ull      // one_hot [BS][K][S]
#define O3 71303169ull     // indices [BS][S] (as float)
#define O4 71368705ull     // distance [BS][K][S]
#define O5 138477569ull    // unquantized [BS*S][D]
#define O6 142671873ull    // embeddings.T [K][D]

// Kernel 0: transpose E -> out6 + aligned ws copy; b2[k] = ||e_k||^2; zero loss.
__global__ __launch_bounds__(256) void vq_prep(const float* __restrict__ E,
                                               float* __restrict__ out,
                                               float* __restrict__ et_ws,
                                               float* __restrict__ b2_ws) {
    __shared__ float T[64][65];
    const int tid  = threadIdx.x;
    const int lane = tid & 63;
    const int sub  = tid >> 6;
    const int k0   = blockIdx.x * 64;
    for (int dd = 0; dd < 16; ++dd) {
        int d = dd * 4 + sub;
        T[d][lane] = E[(size_t)d * KE + k0 + lane];
    }
    __syncthreads();
    for (int ii = 0; ii < 16; ++ii) {
        int kl = ii * 4 + sub;
        float v = T[lane][kl];
        out[O6 + (size_t)(k0 + kl) * 64 + lane] = v;
        et_ws[(size_t)(k0 + kl) * 64 + lane]    = v;
    }
    if (tid < 64) {
        float s = 0.f;
        #pragma unroll
        for (int d = 0; d < 64; ++d) {
            float v = T[d][tid];
            s = fmaf(v, v, s);
        }
        b2_ws[k0 + tid] = s;
    }
    if (blockIdx.x == 0 && tid == 0) out[O1] = 0.f;
}

// Kernel 1: register-tiled SGEMM-style distance + fused one_hot zeros + argmin
// + indices + one_hot fix + quantized + loss.
// grid = 32 b * 16 s-tiles; block 256 = (16 tx)*(16 ky); thread tile 8s x 8k.
__global__ __launch_bounds__(256, 2) void vq_main(const float* __restrict__ x,
                                                  const float* __restrict__ E,
                                                  const float* __restrict__ et,
                                                  const float* __restrict__ b2,
                                                  float* __restrict__ out) {
    __shared__ __align__(16) float xt[64][ST];   // 32 KB, x-tile [d][s]
    __shared__ __align__(16) union UU {
        float e[64][KC];                          // 32 KB, e-chunk [d][k]
        struct { float D[16][ST]; int Kk[16][ST]; } red;   // 16 KB
        float qt[64][ST];                         // 32 KB
    } u;
    __shared__ __align__(16) float a2s[ST];

    const int tid = threadIdx.x;
    const int tx  = tid & 15;      // s-group: s = tx*8 .. +8
    const int ky  = tid >> 4;      // k-group: k = kc + ky*8 .. +8
    const int b   = blockIdx.x >> 4;
    const int s0  = (blockIdx.x & 15) << 7;

    // stage x-tile [64 d][128 s], coalesced float4
    {
        const float* xb = x + ((size_t)b << 17) + s0;    // D*S = 2^17
        #pragma unroll
        for (int i = 0; i < 8; ++i) {
            int f  = (i << 8) + tid;       // 2048 float4s
            int d  = f >> 5;               // 32 f4 per row
            int sc = (f & 31) << 2;
            *(float4*)&xt[d][sc] = *(const float4*)(xb + ((size_t)d << 11) + sc);
        }
    }
    __syncthreads();
    if (tid < ST) {
        float s = 0.f;
        #pragma unroll
        for (int d = 0; d < 64; ++d) s = fmaf(xt[d][tid], xt[d][tid], s);
        a2s[tid] = s;
    }

    float bD[8], a2v[8];
    int   bK[8];
    #pragma unroll
    for (int j = 0; j < 8; ++j) { bD[j] = 3.4e38f; bK[j] = 0; }

    float* outD = out + O4 + ((size_t)b << 21) + s0 + tx * 8;   // K*S = 2^21
    float* outH = out + O2 + ((size_t)b << 21) + s0 + tx * 8;

    for (int c = 0; c < KE / KC; ++c) {
        const int kc = c * KC;
        __syncthreads();   // prev chunk's u.e reads done (also covers a2s/xt first time)
        // stage e-chunk [64 d][128 k] from E's native [d][k] layout
        {
            const float* eb = E + kc;
            #pragma unroll
            for (int i = 0; i < 8; ++i) {
                int f  = (i << 8) + tid;
                int d  = f >> 5;
                int kk = (f & 31) << 2;
                *(float4*)&u.e[d][kk] = *(const float4*)(eb + (size_t)d * KE + kk);
            }
        }
        __syncthreads();

        float acc[8][8];
        #pragma unroll
        for (int jk = 0; jk < 8; ++jk)
            #pragma unroll
            for (int js = 0; js < 8; ++js) acc[jk][js] = 0.f;

        #pragma unroll 2
        for (int d = 0; d < 64; ++d) {
            float4 xa = *(const float4*)&xt[d][tx * 8];
            float4 xb4 = *(const float4*)&xt[d][tx * 8 + 4];
            float4 ea = *(const float4*)&u.e[d][ky * 8];
            float4 eb4 = *(const float4*)&u.e[d][ky * 8 + 4];
            float xs[8] = {xa.x, xa.y, xa.z, xa.w, xb4.x, xb4.y, xb4.z, xb4.w};
            float es[8] = {ea.x, ea.y, ea.z, ea.w, eb4.x, eb4.y, eb4.z, eb4.w};
            #pragma unroll
            for (int jk = 0; jk < 8; ++jk)
                #pragma unroll
                for (int js = 0; js < 8; ++js)
                    acc[jk][js] = fmaf(es[jk], xs[js], acc[jk][js]);
        }

        // epilogue: distance + one_hot zero + argmin
        float4 b2a = *(const float4*)(b2 + kc + ky * 8);
        float4 b2b = *(const float4*)(b2 + kc + ky * 8 + 4);
        float b2v[8] = {b2a.x, b2a.y, b2a.z, b2a.w, b2b.x, b2b.y, b2b.z, b2b.w};
        float4 av1 = *(const float4*)&a2s[tx * 8];
        float4 av2 = *(const float4*)&a2s[tx * 8 + 4];
        a2v[0]=av1.x; a2v[1]=av1.y; a2v[2]=av1.z; a2v[3]=av1.w;
        a2v[4]=av2.x; a2v[5]=av2.y; a2v[6]=av2.z; a2v[7]=av2.w;
        #pragma unroll
        for (int jk = 0; jk < 8; ++jk) {
            const int k = kc + ky * 8 + jk;
            float* pD = outD + ((size_t)k << 11);
            float* pH = outH + ((size_t)k << 11);
            #pragma unroll
            for (int js = 0; js < 8; ++js) {
                float dist = fmaf(-2.f, acc[jk][js], a2v[js] + b2v[jk]);
                pD[js] = dist;      // b32, overwritten-never, coalesces in L2
                pH[js] = 0.f;       // fused one_hot zero
                if (dist < bD[js]) { bD[js] = dist; bK[js] = k; }  // k ascending per thread
            }
        }
    }

    __syncthreads();   // last chunk's u.e reads done before red overwrite
    #pragma unroll
    for (int js = 0; js < 8; ++js) {
        u.red.D[ky][tx * 8 + js]  = bD[js];
        u.red.Kk[ky][tx * 8 + js] = bK[js];
    }
    __syncthreads();

    if (tid < ST) {
        float bDr = u.red.D[0][tid];
        int   bKr = u.red.Kk[0][tid];
        #pragma unroll
        for (int w = 1; w < 16; ++w) {
            float dw = u.red.D[w][tid];
            int   kw = u.red.Kk[w][tid];
            if (dw < bDr || (dw == bDr && kw < bKr)) { bDr = dw; bKr = kw; }  // global first-min
        }
        out[O3 + (size_t)b * SEQ + s0 + tid] = (float)bKr;
        out[O2 + ((size_t)b << 21) + ((size_t)bKr << 11) + s0 + tid] = 1.f;   // same block wrote the 0

        // gather codeword, fill qt column, loss partial (columns are disjoint per thread)
        const float* q = et + ((size_t)bKr << 6);
        float lsum = 0.f;
        #pragma unroll
        for (int i = 0; i < 16; ++i) {
            float4 q4 = ((const float4*)q)[i];
            float qs[4] = {q4.x, q4.y, q4.z, q4.w};
            #pragma unroll
            for (int j = 0; j < 4; ++j) {
                int d = i * 4 + j;
                u.qt[d][tid] = qs[j];
                float df = qs[j] - xt[d][tid];
                lsum = fmaf(df, df, lsum);
            }
        }
        #pragma unroll
        for (int m = 32; m >= 1; m >>= 1) lsum += __shfl_xor(lsum, m, 64);
        if ((tid & 63) == 0) atomicAdd(out + O1, lsum * (2.f / 4194304.f));
    }
    __syncthreads();

    // quantized_st out: [d][s] coalesced float4 (O0 aligned)
    {
        float* oq = out + ((size_t)b << 17) + s0;
        #pragma unroll
        for (int i = 0; i < 8; ++i) {
            int f  = (i << 8) + tid;
            int d  = f >> 5;
            int sc = (f & 31) << 2;
            *(float4*)(oq + ((size_t)d << 11) + sc) = *(const float4*)&u.qt[d][sc];
        }
    }
}

// Kernel 2: unquantized = x transposed to [BS*S][D]
__global__ __launch_bounds__(256) void vq_unq(const float* __restrict__ x,
                                              float* __restrict__ out) {
    __shared__ float T[64][65];
    const int tid  = threadIdx.x;
    const int lane = tid & 63;
    const int sub  = tid >> 6;
    const int b    = blockIdx.x >> 5;
    const int s0   = (blockIdx.x & 31) << 6;
    const float* xp = x + ((size_t)b << 17) + s0;
    for (int dd = 0; dd < 16; ++dd) {
        int d = dd * 4 + sub;
        T[d][lane] = xp[((size_t)d << 11) + lane];
    }
    __syncthreads();
    float* op = out + O5 + (((size_t)b << 11) + s0) * 64;
    for (int ii = 0; ii < 16; ++ii) {
        int sl = ii * 4 + sub;
        op[(size_t)sl * 64 + lane] = T[lane][sl];
    }
}

extern "C" void kernel_launch(void* const* d_in, const int* in_sizes, int n_in,
                              void* d_out, int out_size, void* d_ws, size_t ws_size,
                              hipStream_t stream) {
    const float* x = (const float*)d_in[0];
    const float* E = (const float*)d_in[1];
    float* out   = (float*)d_out;
    float* et_ws = (float*)d_ws;          // 65536 floats: E^T rows, 16B-aligned
    float* b2_ws = et_ws + 65536;         // 1024 floats
    vq_prep<<<16, 256, 0, stream>>>(E, out, et_ws, b2_ws);
    vq_main<<<512, 256, 0, stream>>>(x, E, et_ws, b2_ws, out);
    vq_unq<<<1024, 256, 0, stream>>>(x, out);
}

// Round 5
// 237.927 us; speedup vs baseline: 2.1852x; 1.2346x over previous
//
#include <hip/hip_runtime.h>

#define BSZ 32
#define DIM 64
#define SEQ 2048
#define KE  1024
#define KC  128   // k-chunk staged in LDS
#define ST  128   // s-tile per block

// output offsets in floats
#define O0 0ull            // quantized_st [BS][D][S]
#define O1 4194304ull      // loss (scalar)
#define O2 4194305ull      // one_hot [BS][K][S]
#define O3 71303169ull     // indices [BS][S] (as float)
#define O4 71368705ull     // distance [BS][K][S]
#define O5 138477569ull    // unquantized [BS*S][D]
#define O6 142671873ull    // embeddings.T [K][D]

// Kernel 0: transpose E -> out6 + aligned ws copy; b2[k] = ||e_k||^2; zero loss.
__global__ __launch_bounds__(256) void vq_prep(const float* __restrict__ E,
                                               float* __restrict__ out,
                                               float* __restrict__ et_ws,
                                               float* __restrict__ b2_ws) {
    __shared__ float T[64][65];
    const int tid  = threadIdx.x;
    const int lane = tid & 63;
    const int sub  = tid >> 6;
    const int k0   = blockIdx.x * 64;
    for (int dd = 0; dd < 16; ++dd) {
        int d = dd * 4 + sub;
        T[d][lane] = E[(size_t)d * KE + k0 + lane];
    }
    __syncthreads();
    for (int ii = 0; ii < 16; ++ii) {
        int kl = ii * 4 + sub;
        float v = T[lane][kl];
        out[O6 + (size_t)(k0 + kl) * 64 + lane] = v;
        et_ws[(size_t)(k0 + kl) * 64 + lane]    = v;
    }
    if (tid < 64) {
        float s = 0.f;
        #pragma unroll
        for (int d = 0; d < 64; ++d) {
            float v = T[d][tid];
            s = fmaf(v, v, s);
        }
        b2_ws[k0 + tid] = s;
    }
    if (blockIdx.x == 0 && tid == 0) out[O1] = 0.f;
}

// Kernel 1: register-tiled distance GEMM; dist staged through LDS so ALL global
// stores are lane-consecutive; fused one_hot zeros in the flush; argmin; epilogues.
// grid = 32 b * 16 s-tiles; block 256 = (16 tx)*(16 ky); thread tile 8s x 8k.
__global__ __launch_bounds__(256, 2) void vq_main(const float* __restrict__ x,
                                                  const float* __restrict__ E,
                                                  const float* __restrict__ et,
                                                  const float* __restrict__ b2,
                                                  float* __restrict__ out) {
    __shared__ __align__(16) float xt[64][ST];   // 32 KB, x-tile [d][s]
    __shared__ __align__(16) union UU {
        float e[64][KC];                          // 32 KB e-chunk; reused as dist stage [64][128]
        struct { float D[16][ST]; int Kk[16][ST]; } red;   // 16 KB
        float qt[64][ST];                         // 32 KB
    } u;
    __shared__ __align__(16) float a2s[ST];

    const int tid = threadIdx.x;
    const int tx  = tid & 15;      // s-group: s = tx*8 .. +8
    const int ky  = tid >> 4;      // k-group: k = kc + ky*8 .. +8
    const int b   = blockIdx.x >> 4;
    const int s0  = (blockIdx.x & 15) << 7;

    // stage x-tile [64 d][128 s], coalesced float4
    {
        const float* xb = x + ((size_t)b << 17) + s0;    // D*S = 2^17
        #pragma unroll
        for (int i = 0; i < 8; ++i) {
            int f  = (i << 8) + tid;
            int d  = f >> 5;
            int sc = (f & 31) << 2;
            *(float4*)&xt[d][sc] = *(const float4*)(xb + ((size_t)d << 11) + sc);
        }
    }
    __syncthreads();
    if (tid < ST) {
        float s = 0.f;
        #pragma unroll
        for (int d = 0; d < 64; ++d) s = fmaf(xt[d][tid], xt[d][tid], s);
        a2s[tid] = s;
    }
    // NOTE: a2s consumed after the next __syncthreads() inside the chunk loop.

    float bD[8];
    int   bK[8];
    #pragma unroll
    for (int j = 0; j < 8; ++j) { bD[j] = 3.4e38f; bK[j] = 0; }

    float* outD = out + O4 + ((size_t)b << 21) + s0;   // K*S = 2^21
    float* outH = out + O2 + ((size_t)b << 21) + s0;

    for (int c = 0; c < KE / KC; ++c) {
        const int kc = c << 7;
        __syncthreads();   // ebuf free: prev flush LDS-reads done (first iter: xt/a2s ready)
        // stage e-chunk [64 d][128 k] from E's native [d][k] layout
        {
            const float* eb = E + kc;
            #pragma unroll
            for (int i = 0; i < 8; ++i) {
                int f  = (i << 8) + tid;
                int d  = f >> 5;
                int kk = (f & 31) << 2;
                *(float4*)&u.e[d][kk] = *(const float4*)(eb + (size_t)d * KE + kk);
            }
        }
        __syncthreads();

        float acc[8][8];
        #pragma unroll
        for (int jk = 0; jk < 8; ++jk)
            #pragma unroll
            for (int js = 0; js < 8; ++js) acc[jk][js] = 0.f;

        #pragma unroll 2
        for (int d = 0; d < 64; ++d) {
            float4 xa  = *(const float4*)&xt[d][tx * 8];
            float4 xb4 = *(const float4*)&xt[d][tx * 8 + 4];
            float4 ea  = *(const float4*)&u.e[d][ky * 8];
            float4 eb4 = *(const float4*)&u.e[d][ky * 8 + 4];
            float xs[8] = {xa.x, xa.y, xa.z, xa.w, xb4.x, xb4.y, xb4.z, xb4.w};
            float es[8] = {ea.x, ea.y, ea.z, ea.w, eb4.x, eb4.y, eb4.z, eb4.w};
            #pragma unroll
            for (int jk = 0; jk < 8; ++jk)
                #pragma unroll
                for (int js = 0; js < 8; ++js)
                    acc[jk][js] = fmaf(es[jk], xs[js], acc[jk][js]);
        }

        // dist in-place + per-thread argmin (k ascending per thread)
        {
            float4 b2a = *(const float4*)(b2 + kc + ky * 8);
            float4 b2b = *(const float4*)(b2 + kc + ky * 8 + 4);
            float b2v[8] = {b2a.x, b2a.y, b2a.z, b2a.w, b2b.x, b2b.y, b2b.z, b2b.w};
            float4 av1 = *(const float4*)&a2s[tx * 8];
            float4 av2 = *(const float4*)&a2s[tx * 8 + 4];
            float a2v[8] = {av1.x, av1.y, av1.z, av1.w, av2.x, av2.y, av2.z, av2.w};
            #pragma unroll
            for (int jk = 0; jk < 8; ++jk) {
                const int k = kc + ky * 8 + jk;
                #pragma unroll
                for (int js = 0; js < 8; ++js) {
                    float dist = fmaf(-2.f, acc[jk][js], a2v[js] + b2v[jk]);
                    acc[jk][js] = dist;
                    if (dist < bD[js]) { bD[js] = dist; bK[js] = k; }
                }
            }
        }

        // flush dist + one_hot zeros via LDS stage (e-chunk is dead now):
        // half h covers k-rows [kc+64h, +64); wave-pair h writes, all flush.
        #pragma unroll
        for (int h = 0; h < 2; ++h) {
            __syncthreads();   // h=0: e-reads done; h=1: previous flush LDS-reads done
            if ((ky >> 3) == h) {
                const int r0 = (ky & 7) * 8;
                #pragma unroll
                for (int jk = 0; jk < 8; ++jk) {
                    float4 lo = {acc[jk][0], acc[jk][1], acc[jk][2], acc[jk][3]};
                    float4 hi = {acc[jk][4], acc[jk][5], acc[jk][6], acc[jk][7]};
                    *(float4*)&u.e[r0 + jk][tx * 8]     = lo;
                    *(float4*)&u.e[r0 + jk][tx * 8 + 4] = hi;
                }
            }
            __syncthreads();
            const int kb = kc + (h << 6);
            const float* st = (const float*)u.e;
            #pragma unroll
            for (int i = 0; i < 32; ++i) {
                int f   = (i << 8) + tid;       // 0..8191, lane-consecutive
                int row = f >> 7;
                int sc  = f & 127;
                size_t off = ((size_t)(kb + row) << 11) + sc;
                outD[off] = st[f];    // 64 consecutive lanes -> 4 lines/instr
                outH[off] = 0.f;      // fused one_hot zero, same pattern
            }
        }
    }

    __syncthreads();   // last flush LDS-reads done before red overwrite
    #pragma unroll
    for (int js = 0; js < 8; ++js) {
        u.red.D[ky][tx * 8 + js]  = bD[js];
        u.red.Kk[ky][tx * 8 + js] = bK[js];
    }
    __syncthreads();

    if (tid < ST) {
        float bDr = u.red.D[0][tid];
        int   bKr = u.red.Kk[0][tid];
        #pragma unroll
        for (int w = 1; w < 16; ++w) {
            float dw = u.red.D[w][tid];
            int   kw = u.red.Kk[w][tid];
            if (dw < bDr || (dw == bDr && kw < bKr)) { bDr = dw; bKr = kw; }  // global first-min
        }
        out[O3 + (size_t)b * SEQ + s0 + tid] = (float)bKr;
        out[O2 + ((size_t)b << 21) + ((size_t)bKr << 11) + s0 + tid] = 1.f;   // after all zeros (vmcnt drained at barriers)

        // gather codeword, fill qt column, loss partial
        const float* q = et + ((size_t)bKr << 6);
        float lsum = 0.f;
        #pragma unroll
        for (int i = 0; i < 16; ++i) {
            float4 q4 = ((const float4*)q)[i];
            float qs[4] = {q4.x, q4.y, q4.z, q4.w};
            #pragma unroll
            for (int j = 0; j < 4; ++j) {
                int d = i * 4 + j;
                u.qt[d][tid] = qs[j];
                float df = qs[j] - xt[d][tid];
                lsum = fmaf(df, df, lsum);
            }
        }
        #pragma unroll
        for (int m = 32; m >= 1; m >>= 1) lsum += __shfl_xor(lsum, m, 64);
        if ((tid & 63) == 0) atomicAdd(out + O1, lsum * (2.f / 4194304.f));
    }
    __syncthreads();

    // quantized_st out: [d][s] coalesced float4 (O0 aligned)
    {
        float* oq = out + ((size_t)b << 17) + s0;
        #pragma unroll
        for (int i = 0; i < 8; ++i) {
            int f  = (i << 8) + tid;
            int d  = f >> 5;
            int sc = (f & 31) << 2;
            *(float4*)(oq + ((size_t)d << 11) + sc) = *(const float4*)&u.qt[d][sc];
        }
    }
}

// Kernel 2: unquantized = x transposed to [BS*S][D]
__global__ __launch_bounds__(256) void vq_unq(const float* __restrict__ x,
                                              float* __restrict__ out) {
    __shared__ float T[64][65];
    const int tid  = threadIdx.x;
    const int lane = tid & 63;
    const int sub  = tid >> 6;
    const int b    = blockIdx.x >> 5;
    const int s0   = (blockIdx.x & 31) << 6;
    const float* xp = x + ((size_t)b << 17) + s0;
    for (int dd = 0; dd < 16; ++dd) {
        int d = dd * 4 + sub;
        T[d][lane] = xp[((size_t)d << 11) + lane];
    }
    __syncthreads();
    float* op = out + O5 + (((size_t)b << 11) + s0) * 64;
    for (int ii = 0; ii < 16; ++ii) {
        int sl = ii * 4 + sub;
        op[(size_t)sl * 64 + lane] = T[lane][sl];
    }
}

extern "C" void kernel_launch(void* const* d_in, const int* in_sizes, int n_in,
                              void* d_out, int out_size, void* d_ws, size_t ws_size,
                              hipStream_t stream) {
    const float* x = (const float*)d_in[0];
    const float* E = (const float*)d_in[1];
    float* out   = (float*)d_out;
    float* et_ws = (float*)d_ws;          // 65536 floats: E^T rows, 16B-aligned
    float* b2_ws = et_ws + 65536;         // 1024 floats
    vq_prep<<<16, 256, 0, stream>>>(E, out, et_ws, b2_ws);
    vq_main<<<512, 256, 0, stream>>>(x, E, et_ws, b2_ws, out);
    vq_unq<<<1024, 256, 0, stream>>>(x, out);
}